// Round 8
// baseline (163.162 us; speedup 1.0000x reference)
//
#include <hip/hip_runtime.h>
#include <hip/hip_bf16.h>
#include <stdint.h>

// GAT layer: N=8192, F_IN=256, F_OUT=64, two branches (adj_in/adj_out), shared 'a'.

#define NN 8192
#define ALPHA 0.2f
#define L2E 1.44269504088896f
#define AL2E 0.288539008177792f   // 0.2 * log2(e)

typedef _Float16 f16;
typedef _Float16 f16x2 __attribute__((ext_vector_type(2)));
typedef _Float16 f16x4 __attribute__((ext_vector_type(4)));
typedef _Float16 f16x8 __attribute__((ext_vector_type(8)));
typedef float f32x4 __attribute__((ext_vector_type(4)));
typedef unsigned int u32;

// workspace layout (bytes). E1/E2 overlay WT (dead after k2).
#define WS_WT    0u         // f16 [128][256]
#define WS_E1    0u         // f16 [2][8192]
#define WS_E2    32768u     // f16 [2][8192]
#define WS_HT    65536u     // f16 [2][1024][64][8] blocked: HTB[b][j>>3][c][j&7]
#define WS_SRC   2162688u   // f32 [2][8192]
#define WS_DST   2228224u   // f32 [2][8192]
#define WS_DMAX  2293760u   // f32 [2]
#define WS_PACC  2294016u   // f32 [2][8192][64]

static __device__ __forceinline__ void gload16(const void* g, void* l) {
    __builtin_amdgcn_global_load_lds(
        (const __attribute__((address_space(1))) void*)g,
        (__attribute__((address_space(3))) void*)l, 16, 0, 0);
}

// ---------------- kernel 1: WT[c][k] = W[k][c] as f16 ----------------
__global__ __launch_bounds__(256) void k1_wt(const float* __restrict__ Win,
                                             const float* __restrict__ Wout,
                                             f16* __restrict__ WT) {
    int c = blockIdx.x;
    int k = threadIdx.x;
    const float* W = (c < 64) ? Win : Wout;
    int cc = c & 63;
    WT[(size_t)c * 256 + k] = (f16)W[(size_t)k * 64 + cc];
}

// ---------------- kernel 2: h = x@W (MFMA), emit blocked HTB f16 + src/dst ----------------
__global__ __launch_bounds__(64) void k2_h(const float* __restrict__ x,
                                           const f16* __restrict__ WT,
                                           const float* __restrict__ a,
                                           f16* __restrict__ HT,
                                           float* __restrict__ srcw,
                                           float* __restrict__ dstw) {
    int l = threadIdx.x;
    int l15 = l & 15, lhi = l >> 4;
    int row0 = blockIdx.x * 16;

    f32x4 acc[8];
#pragma unroll
    for (int n = 0; n < 8; n++) { acc[n][0]=0.f; acc[n][1]=0.f; acc[n][2]=0.f; acc[n][3]=0.f; }

#pragma unroll
    for (int kc = 0; kc < 8; kc++) {
        int k = kc * 32 + lhi * 8;
        const float* xp = x + (size_t)(row0 + l15) * 256 + k;
        float4 xa = *(const float4*)xp;
        float4 xb = *(const float4*)(xp + 4);
        f16x8 af;
        af[0]=(f16)xa.x; af[1]=(f16)xa.y; af[2]=(f16)xa.z; af[3]=(f16)xa.w;
        af[4]=(f16)xb.x; af[5]=(f16)xb.y; af[6]=(f16)xb.z; af[7]=(f16)xb.w;
#pragma unroll
        for (int n = 0; n < 8; n++) {
            f16x8 bf = *(const f16x8*)(WT + (size_t)(16 * n + l15) * 256 + k);
            acc[n] = __builtin_amdgcn_mfma_f32_16x16x32_f16(af, bf, acc[n], 0, 0, 0);
        }
    }

    float as4[4], ad4[4];
#pragma unroll
    for (int nn = 0; nn < 4; nn++) {
        as4[nn] = a[16 * nn + l15];
        ad4[nn] = a[64 + 16 * nn + l15];
    }

    float s_in[4] = {0,0,0,0}, d_in[4] = {0,0,0,0};
    float s_out[4] = {0,0,0,0}, d_out[4] = {0,0,0,0};

#pragma unroll
    for (int n = 0; n < 8; n++) {
        int b = n >> 2;
        int ci = 16 * (n & 3) + l15;
        int jj = row0 + 4 * lhi;
        f16x4 hv;
#pragma unroll
        for (int q = 0; q < 4; q++) hv[q] = (f16)acc[n][q];
        *(f16x4*)(HT + (size_t)b * 524288 + (size_t)(jj >> 3) * 512 + (size_t)ci * 8 + (jj & 7)) = hv;
#pragma unroll
        for (int q = 0; q < 4; q++) {
            float v = acc[n][q];
            if (b == 0) { s_in[q]  += v * as4[n & 3]; d_in[q]  += v * ad4[n & 3]; }
            else        { s_out[q] += v * as4[n & 3]; d_out[q] += v * ad4[n & 3]; }
        }
    }

#pragma unroll
    for (int q = 0; q < 4; q++) {
#pragma unroll
        for (int m = 1; m < 16; m <<= 1) {
            s_in[q]  += __shfl_xor(s_in[q],  m, 64);
            d_in[q]  += __shfl_xor(d_in[q],  m, 64);
            s_out[q] += __shfl_xor(s_out[q], m, 64);
            d_out[q] += __shfl_xor(d_out[q], m, 64);
        }
    }
    if (l15 == 0) {
        int row = row0 + 4 * lhi;
#pragma unroll
        for (int q = 0; q < 4; q++) {
            srcw[row + q]        = s_in[q];
            srcw[8192 + row + q] = s_out[q];
            dstw[row + q]        = d_in[q];
            dstw[8192 + row + q] = d_out[q];
        }
    }
}

// ---------------- kernel 3: per-branch max of dst ----------------
__global__ __launch_bounds__(256) void k3_dmax(const float* __restrict__ dstw,
                                               float* __restrict__ dmax) {
    __shared__ float red[2][4];
    int t = threadIdx.x;
    int l = t & 63, w = t >> 6;
    for (int b = 0; b < 2; b++) {
        float v = -1e30f;
        for (int i = t; i < 8192; i += 256) v = fmaxf(v, dstw[b * 8192 + i]);
#pragma unroll
        for (int m = 1; m < 64; m <<= 1) v = fmaxf(v, __shfl_xor(v, m, 64));
        if (l == 0) red[b][w] = v;
    }
    __syncthreads();
    if (t == 0) dmax[0] = fmaxf(fmaxf(red[0][0], red[0][1]), fmaxf(red[0][2], red[0][3]));
    if (t == 1) dmax[1] = fmaxf(fmaxf(red[1][0], red[1][1]), fmaxf(red[1][2], red[1][3]));
}

// ---------------- kernel 3b: E tables, f16, normalized by dmax ----------------
__global__ __launch_bounds__(256) void k3b_e(const float* __restrict__ dstw,
                                             const float* __restrict__ dmax,
                                             f16* __restrict__ E1,
                                             f16* __restrict__ E2) {
    int i = blockIdx.x * 256 + threadIdx.x;
    int b = i >> 13;
    float d = dstw[i] - dmax[b];
    E1[i] = (f16)exp2f(d * L2E);
    E2[i] = (f16)exp2f(d * AL2E);
}

// ---------------- kernel 4: fused masked-softmax-attention, deep DMA pipeline ----------------
// Block = 4 waves, 16 rows, one branch. j tiled by 256. adj staged via
// coalesced global_load_lds into a 3-deep LDS ring (48 KB), stage issued 2
// tiles ahead. Raw s_barrier (no drain); explicit counted s_waitcnt vmcnt(4)
// keeps the newest stage in flight across the barrier. 3 blocks/CU (12 waves).
__global__ __launch_bounds__(256, 3) void k4_main(const int* __restrict__ adj_in,
                                                  const int* __restrict__ adj_out,
                                                  const f16* __restrict__ HT,
                                                  const float* __restrict__ srcw,
                                                  const float* __restrict__ dmaxp,
                                                  const f16* __restrict__ E1g,
                                                  const f16* __restrict__ E2g,
                                                  float* __restrict__ pacc) {
    __shared__ __align__(16) char lds[49664];   // 3 x 16KB adj ring; epilogue reuses

    int t = threadIdx.x;
    int branch = blockIdx.x & 1;
    int row0 = (blockIdx.x >> 1) * 16;
    const int* adj = (branch ? adj_out : adj_in) + (size_t)row0 * NN;
    const f16* htg = HT + (size_t)branch * (64 * NN);
    const f16* e1b = E1g + branch * NN;
    const f16* e2b = E2g + branch * NN;

    int l = t & 63, wv = t >> 6;
    int l15 = l & 15, lhi = l >> 4;
    int sw = l15 & 7;

    // per-row constants: ev = max(k1*E1[j], k2*E2[j]) = exp2(LR(src+d)*L2E - mlog)
    float srcv = srcw[branch * NN + row0 + l15];
    float dmaxv = dmaxp[branch];
    float md = srcv + dmaxv;
    float mlog = fmaxf(md, ALPHA * md) * L2E;
    f16 k1h = (f16)exp2f(md * L2E - mlog);
    f16 k2h = (f16)exp2f(ALPHA * md * L2E - mlog);
    f16x8 k1v, k2v;
#pragma unroll
    for (int i = 0; i < 8; i++) { k1v[i] = k1h; k2v[i] = k2h; }

    f32x4 acc[4];
#pragma unroll
    for (int n = 0; n < 4; n++) { acc[n][0]=0.f; acc[n][1]=0.f; acc[n][2]=0.f; acc[n][3]=0.f; }
    float dn = 0.f;
    f16x2 one2; one2[0] = (f16)1.f; one2[1] = (f16)1.f;

    auto stage = [&](int tile, int buf) {
        const int* base = adj + tile * 256;
#pragma unroll
        for (int i = 0; i < 4; i++) {
            int r = wv * 4 + i;
            const int* src = base + (size_t)r * NN + ((l ^ (r & 7)) << 2);
            gload16(src, lds + buf * 16384 + r * 1024);
        }
    };

    // prologue: stages 0 and 1 in flight; require stage 0 complete only.
    stage(0, 0);
    stage(1, 1);
    asm volatile("s_waitcnt vmcnt(4)");          // stage1's 4 loads may remain
    __builtin_amdgcn_sched_barrier(0);
    __builtin_amdgcn_s_barrier();

    int buf = 0;                                  // tile % 3
    for (int tile = 0; tile < 32; tile++) {
        const char* rowp = lds + buf * 16384 + l15 * 1024;

        // 1) adj for both ss slices from LDS (lgkm-waited by compiler)
        int qb0 = (wv * 64 >> 2) + 2 * lhi;
        int4 a0 = *(const int4*)(rowp + (((qb0    ) ^ sw) << 4));
        int4 a1 = *(const int4*)(rowp + (((qb0 + 1) ^ sw) << 4));
        int qb1 = qb0 + 8;
        int4 a2 = *(const int4*)(rowp + (((qb1    ) ^ sw) << 4));
        int4 a3 = *(const int4*)(rowp + (((qb1 + 1) ^ sw) << 4));

        // 2) E/HT register loads for this tile (L2-resident)
        int jg0 = tile * 256 + wv * 64 + lhi * 8;
        int jg1 = jg0 + 32;
        f16x8 e1v0 = *(const f16x8*)(e1b + jg0);
        f16x8 e2v0 = *(const f16x8*)(e2b + jg0);
        f16x8 e1v1 = *(const f16x8*)(e1b + jg1);
        f16x8 e2v1 = *(const f16x8*)(e2b + jg1);
        const f16* hb0 = htg + (size_t)(jg0 >> 3) * 512 + l15 * 8;
        const f16* hb1 = htg + (size_t)(jg1 >> 3) * 512 + l15 * 8;
        f16x8 b00 = *(const f16x8*)(hb0);
        f16x8 b01 = *(const f16x8*)(hb0 + 128);
        f16x8 b02 = *(const f16x8*)(hb0 + 256);
        f16x8 b03 = *(const f16x8*)(hb0 + 384);
        f16x8 b10 = *(const f16x8*)(hb1);
        f16x8 b11 = *(const f16x8*)(hb1 + 128);
        f16x8 b12 = *(const f16x8*)(hb1 + 256);
        f16x8 b13 = *(const f16x8*)(hb1 + 384);
        __builtin_amdgcn_sched_barrier(0);

        // 3) stage tile+2 into buf (tile+2)%3 == (buf+2)%3
        int sbuf = (buf == 0) ? 2 : buf - 1;     // (buf+2)%3
        if (tile < 30) stage(tile + 2, sbuf);
        __builtin_amdgcn_sched_barrier(0);

        // 4) masks + weights + MFMA, slice 0
        {
            union { u32 u[4]; f16x8 h; } mu;
            mu.u[0] = (u32)(a0.x + (a0.y << 16)) * 0x3C00u;
            mu.u[1] = (u32)(a0.z + (a0.w << 16)) * 0x3C00u;
            mu.u[2] = (u32)(a1.x + (a1.y << 16)) * 0x3C00u;
            mu.u[3] = (u32)(a1.z + (a1.w << 16)) * 0x3C00u;
            f16x8 w = __builtin_elementwise_max(e1v0 * k1v, e2v0 * k2v) * mu.h;
            union { f16x8 h; f16x2 p[4]; } wu; wu.h = w;
#if __has_builtin(__builtin_amdgcn_fdot2)
            dn = __builtin_amdgcn_fdot2(wu.p[0], one2, dn, false);
            dn = __builtin_amdgcn_fdot2(wu.p[1], one2, dn, false);
            dn = __builtin_amdgcn_fdot2(wu.p[2], one2, dn, false);
            dn = __builtin_amdgcn_fdot2(wu.p[3], one2, dn, false);
#else
#pragma unroll
            for (int e = 0; e < 8; e++) dn += (float)w[e];
#endif
            acc[0] = __builtin_amdgcn_mfma_f32_16x16x32_f16(w, b00, acc[0], 0, 0, 0);
            acc[1] = __builtin_amdgcn_mfma_f32_16x16x32_f16(w, b01, acc[1], 0, 0, 0);
            acc[2] = __builtin_amdgcn_mfma_f32_16x16x32_f16(w, b02, acc[2], 0, 0, 0);
            acc[3] = __builtin_amdgcn_mfma_f32_16x16x32_f16(w, b03, acc[3], 0, 0, 0);
        }
        // 5) slice 1
        {
            union { u32 u[4]; f16x8 h; } mu;
            mu.u[0] = (u32)(a2.x + (a2.y << 16)) * 0x3C00u;
            mu.u[1] = (u32)(a2.z + (a2.w << 16)) * 0x3C00u;
            mu.u[2] = (u32)(a3.x + (a3.y << 16)) * 0x3C00u;
            mu.u[3] = (u32)(a3.z + (a3.w << 16)) * 0x3C00u;
            f16x8 w = __builtin_elementwise_max(e1v1 * k1v, e2v1 * k2v) * mu.h;
            union { f16x8 h; f16x2 p[4]; } wu; wu.h = w;
#if __has_builtin(__builtin_amdgcn_fdot2)
            dn = __builtin_amdgcn_fdot2(wu.p[0], one2, dn, false);
            dn = __builtin_amdgcn_fdot2(wu.p[1], one2, dn, false);
            dn = __builtin_amdgcn_fdot2(wu.p[2], one2, dn, false);
            dn = __builtin_amdgcn_fdot2(wu.p[3], one2, dn, false);
#else
#pragma unroll
            for (int e = 0; e < 8; e++) dn += (float)w[e];
#endif
            acc[0] = __builtin_amdgcn_mfma_f32_16x16x32_f16(w, b10, acc[0], 0, 0, 0);
            acc[1] = __builtin_amdgcn_mfma_f32_16x16x32_f16(w, b11, acc[1], 0, 0, 0);
            acc[2] = __builtin_amdgcn_mfma_f32_16x16x32_f16(w, b12, acc[2], 0, 0, 0);
            acc[3] = __builtin_amdgcn_mfma_f32_16x16x32_f16(w, b13, acc[3], 0, 0, 0);
        }

        // 6) counted wait: stage(tile+1) must be complete for the next iter;
        //    stage(tile+2) (this wave's newest 4 loads) stays in flight.
        asm volatile("s_waitcnt vmcnt(4)");
        __builtin_amdgcn_sched_barrier(0);
        __builtin_amdgcn_s_barrier();
        buf = (buf == 2) ? 0 : buf + 1;
    }

    // epilogue: reduce dn, merge 4 waves' partials (reuse ring LDS after full drain)
    dn += __shfl_xor(dn, 16, 64);
    dn += __shfl_xor(dn, 32, 64);
    __syncthreads();   // full drain OK here (loop done)

    float* accL = (float*)lds;               // [4][16][64] = 16 KB
    float* dnp  = (float*)(lds + 16384);     // [4][16]
    float* dnr  = (float*)(lds + 16384 + 256);
    if (lhi == 0) dnp[wv * 16 + l15] = dn;
#pragma unroll
    for (int n = 0; n < 4; n++)
#pragma unroll
        for (int q = 0; q < 4; q++)
            accL[wv * 1024 + (4 * lhi + q) * 64 + 16 * n + l15] = acc[n][q];
    __syncthreads();

    if (t < 16) dnr[t] = 1.0f / (dnp[t] + dnp[16 + t] + dnp[32 + t] + dnp[48 + t]);
    __syncthreads();

    int r = t >> 4;
    int c4 = (t & 15) * 4;
    float inv = dnr[r];
    float4 o;
    o.x = (accL[r*64+c4+0] + accL[1024+r*64+c4+0] + accL[2048+r*64+c4+0] + accL[3072+r*64+c4+0]) * inv;
    o.y = (accL[r*64+c4+1] + accL[1024+r*64+c4+1] + accL[2048+r*64+c4+1] + accL[3072+r*64+c4+1]) * inv;
    o.z = (accL[r*64+c4+2] + accL[1024+r*64+c4+2] + accL[2048+r*64+c4+2] + accL[3072+r*64+c4+2]) * inv;
    o.w = (accL[r*64+c4+3] + accL[1024+r*64+c4+3] + accL[2048+r*64+c4+3] + accL[3072+r*64+c4+3]) * inv;
    *(float4*)(pacc + (size_t)branch * 524288 + (size_t)(row0 + r) * 64 + c4) = o;
}

// ---------------- kernel 5: combine branches + ELU ----------------
__global__ __launch_bounds__(256) void k5_combine(const float* __restrict__ pacc,
                                                  float* __restrict__ out) {
    size_t idx = (size_t)blockIdx.x * 256 + threadIdx.x;
    float4 p0 = *(const float4*)(pacc + idx * 4);
    float4 p1 = *(const float4*)(pacc + 524288 + idx * 4);
    float4 o;
    float v;
    v = 0.5f * (p0.x + p1.x); o.x = (v > 0.f) ? v : (exp2f(v * L2E) - 1.f);
    v = 0.5f * (p0.y + p1.y); o.y = (v > 0.f) ? v : (exp2f(v * L2E) - 1.f);
    v = 0.5f * (p0.z + p1.z); o.z = (v > 0.f) ? v : (exp2f(v * L2E) - 1.f);
    v = 0.5f * (p0.w + p1.w); o.w = (v > 0.f) ? v : (exp2f(v * L2E) - 1.f);
    *(float4*)(out + idx * 4) = o;
}

extern "C" void kernel_launch(void* const* d_in, const int* in_sizes, int n_in,
                              void* d_out, int out_size, void* d_ws, size_t ws_size,
                              hipStream_t stream) {
    const float* x       = (const float*)d_in[0];
    const int*   adj_in  = (const int*)d_in[1];
    const int*   adj_out = (const int*)d_in[2];
    const float* W_in    = (const float*)d_in[3];
    const float* W_out   = (const float*)d_in[4];
    const float* a       = (const float*)d_in[5];
    float* out = (float*)d_out;

    char* ws = (char*)d_ws;
    f16*   WT   = (f16*)(ws + WS_WT);
    f16*   E1   = (f16*)(ws + WS_E1);
    f16*   E2   = (f16*)(ws + WS_E2);
    f16*   HT   = (f16*)(ws + WS_HT);
    float* srcw = (float*)(ws + WS_SRC);
    float* dstw = (float*)(ws + WS_DST);
    float* dmax = (float*)(ws + WS_DMAX);
    float* pacc = (float*)(ws + WS_PACC);
    // requires ws_size >= ~6.2 MB

    hipLaunchKernelGGL(k1_wt,     dim3(128),  dim3(256), 0, stream, W_in, W_out, WT);
    hipLaunchKernelGGL(k2_h,      dim3(512),  dim3(64),  0, stream, x, WT, a, HT, srcw, dstw);
    hipLaunchKernelGGL(k3_dmax,   dim3(1),    dim3(256), 0, stream, dstw, dmax);
    hipLaunchKernelGGL(k3b_e,     dim3(64),   dim3(256), 0, stream, dstw, dmax, E1, E2);
    hipLaunchKernelGGL(k4_main,   dim3(1024), dim3(256), 0, stream, adj_in, adj_out, HT, srcw, dmax, E1, E2, pacc);
    hipLaunchKernelGGL(k5_combine,dim3(512),  dim3(256), 0, stream, pacc, out);
}